// Round 17
// baseline (450.729 us; speedup 1.0000x reference)
//
#include <hip/hip_runtime.h>
#include <cstdint>
#include <cstddef>

#define S_LEN 2048
#define BATCH 2
#define HIDN  2048
#define NHEAD 16
#define DHEAD 128
#define NQKV  6144   // 3*NHEAD*DHEAD
#define MROWS 4096   // S_LEN*BATCH

typedef unsigned short u16;
typedef __attribute__((ext_vector_type(8))) __bf16 bf16x8;
typedef __attribute__((ext_vector_type(4))) float f32x4;

__device__ __forceinline__ float bf2f(u16 u) {
  union { uint32_t i; float f; } v; v.i = ((uint32_t)u) << 16; return v.f;
}
__device__ __forceinline__ u16 f2bf(float f) {
  union { float f; uint32_t i; } v; v.f = f;
  uint32_t r = v.i + 0x7fffu + ((v.i >> 16) & 1u);
  return (u16)(r >> 16);
}

__device__ __forceinline__ void async_cp16(const u16* g, u16* l) {
  __builtin_amdgcn_global_load_lds(
      (const __attribute__((address_space(1))) void*)g,
      (__attribute__((address_space(3))) void*)l, 16, 0, 0);
}

// ---------------- hidden canonicalize: fp32[N] -> bf16[N] --------------------
__global__ __launch_bounds__(256) void convert_hidden_kernel(
    const float* __restrict__ src, u16* __restrict__ out) {
  size_t c = (size_t)blockIdx.x * 256 + threadIdx.x;  // chunk of 8 elements
  const float4* in = (const float4*)(src + c * 8);
  float4 v0 = in[0], v1 = in[1];
  u16 t[8] = {f2bf(v0.x), f2bf(v0.y), f2bf(v0.z), f2bf(v0.w),
              f2bf(v1.x), f2bf(v1.y), f2bf(v1.z), f2bf(v1.w)};
  *(uint4*)&out[c * 8] = *(const uint4*)t;
}

// ---------------- transpose+cast: fp32 in[R][C] -> bf16 out[C][R] ------------
__global__ __launch_bounds__(256) void transpose_kernel(
    const float* __restrict__ in, u16* __restrict__ out, int R, int C) {
  __shared__ u16 tile[64][72];
  const int bx = blockIdx.x * 64;  // col base in `in`
  const int by = blockIdx.y * 64;  // row base in `in`
  const int lx = threadIdx.x & 15, ly = threadIdx.x >> 4;
#pragma unroll
  for (int i = 0; i < 4; i++) {
    int r = ly * 4 + i;
    float4 v = *(const float4*)&in[(size_t)(by + r) * C + bx + lx * 4];
    tile[r][lx * 4 + 0] = f2bf(v.x); tile[r][lx * 4 + 1] = f2bf(v.y);
    tile[r][lx * 4 + 2] = f2bf(v.z); tile[r][lx * 4 + 3] = f2bf(v.w);
  }
  __syncthreads();
#pragma unroll
  for (int i = 0; i < 4; i++) {
    int oc = ly * 4 + i;  // out row = bx + oc
    ushort4 o;
    o.x = tile[lx * 4 + 0][oc]; o.y = tile[lx * 4 + 1][oc];
    o.z = tile[lx * 4 + 2][oc]; o.w = tile[lx * 4 + 3][oc];
    *(ushort4*)&out[(size_t)(bx + oc) * R + by + lx * 4] = o;
  }
}

// =============================================================================
// 2-phase 128x128 GEMM core, BK=64, 4 waves (2x2, 64x64 wave tile).
// Round-15 PM: 128x256/8-wave/96KB-LDS ran 1 block/CU -- zero cross-block
// overlap; MfmaUtil pinned at 29% across all barrier/XCD variants (~50% of
// K-tile time = unhidden serial latency). This shape: 64KB LDS + VGPR<=128
// (launch_bounds(256,4)) -> 2 blocks/CU co-resident; barrier stalls of one
// block hide under the other's compute (m97/m114 mechanism, 912 TF verified).
// Schedule per K-tile (unchanged 2-phase): reads x16; B1; lgkm(0); 16 MFMA;
// B2; STAGE8 (tile t+2, same buf -- WAR-safe after B2); 16 MFMA (reg-only);
// vmcnt(8) (waits t+1, issued a full K-tile ago); B3. vmcnt never 0 in loop.
// Swizzle unchanged (row stride still 128B; 2-way residual = free).
// =============================================================================

__device__ __forceinline__ int swz(int o) {
  return o ^ ((o >> 3) & 16) ^ ((o >> 4) & 0x60);
}

__device__ __forceinline__ bf16x8 rdfrag(const u16* ldsT, int row, int lhi16, int kk) {
  int off = row * 128 + kk * 64 + lhi16;
  off ^= ((off >> 3) & 16) ^ ((off >> 4) & 0x60);
  return *(const bf16x8*)((const char*)ldsT + off);
}

#define MFMA16(a, b, c) __builtin_amdgcn_mfma_f32_16x16x32_bf16(a, b, c, 0, 0, 0)

#define STAGE8(d, koff) do {                                            \
    async_cp16(gA[0] + (koff), lA[d] + wq);                             \
    async_cp16(gA[1] + (koff), lA[d] + 2048 + wq);                      \
    async_cp16(gA[2] + (koff), lA[d] + 4096 + wq);                      \
    async_cp16(gA[3] + (koff), lA[d] + 6144 + wq);                      \
    async_cp16(gB[0] + (koff), lB[d] + wq);                             \
    async_cp16(gB[1] + (koff), lB[d] + 2048 + wq);                      \
    async_cp16(gB[2] + (koff), lB[d] + 4096 + wq);                      \
    async_cp16(gB[3] + (koff), lB[d] + 6144 + wq);                      \
  } while (0)

#define KTILE(d, pre_koff) do {                                                 \
    bf16x8 a00, a01, a10, a11, a20, a21, a30, a31;                              \
    bf16x8 b00, b01, b10, b11, b20, b21, b30, b31;                              \
    a00 = rdfrag(lA[d], wm + llo,      lhi16, 0);                               \
    a01 = rdfrag(lA[d], wm + llo,      lhi16, 1);                               \
    a10 = rdfrag(lA[d], wm + 16 + llo, lhi16, 0);                               \
    a11 = rdfrag(lA[d], wm + 16 + llo, lhi16, 1);                               \
    a20 = rdfrag(lA[d], wm + 32 + llo, lhi16, 0);                               \
    a21 = rdfrag(lA[d], wm + 32 + llo, lhi16, 1);                               \
    a30 = rdfrag(lA[d], wm + 48 + llo, lhi16, 0);                               \
    a31 = rdfrag(lA[d], wm + 48 + llo, lhi16, 1);                               \
    b00 = rdfrag(lB[d], wn + llo,      lhi16, 0);                               \
    b01 = rdfrag(lB[d], wn + llo,      lhi16, 1);                               \
    b10 = rdfrag(lB[d], wn + 16 + llo, lhi16, 0);                               \
    b11 = rdfrag(lB[d], wn + 16 + llo, lhi16, 1);                               \
    b20 = rdfrag(lB[d], wn + 32 + llo, lhi16, 0);                               \
    b21 = rdfrag(lB[d], wn + 32 + llo, lhi16, 1);                               \
    b30 = rdfrag(lB[d], wn + 48 + llo, lhi16, 0);                               \
    b31 = rdfrag(lB[d], wn + 48 + llo, lhi16, 1);                               \
    __builtin_amdgcn_s_barrier();                                               \
    asm volatile("s_waitcnt lgkmcnt(0)" ::: "memory");                          \
    __builtin_amdgcn_sched_barrier(0);                                          \
    __builtin_amdgcn_s_setprio(1);                                              \
    acc[0][0] = MFMA16(a00, b00, acc[0][0]); acc[0][0] = MFMA16(a01, b01, acc[0][0]); \
    acc[0][1] = MFMA16(a00, b10, acc[0][1]); acc[0][1] = MFMA16(a01, b11, acc[0][1]); \
    acc[0][2] = MFMA16(a00, b20, acc[0][2]); acc[0][2] = MFMA16(a01, b21, acc[0][2]); \
    acc[0][3] = MFMA16(a00, b30, acc[0][3]); acc[0][3] = MFMA16(a01, b31, acc[0][3]); \
    acc[1][0] = MFMA16(a10, b00, acc[1][0]); acc[1][0] = MFMA16(a11, b01, acc[1][0]); \
    acc[1][1] = MFMA16(a10, b10, acc[1][1]); acc[1][1] = MFMA16(a11, b11, acc[1][1]); \
    acc[1][2] = MFMA16(a10, b20, acc[1][2]); acc[1][2] = MFMA16(a11, b21, acc[1][2]); \
    acc[1][3] = MFMA16(a10, b30, acc[1][3]); acc[1][3] = MFMA16(a11, b31, acc[1][3]); \
    __builtin_amdgcn_s_setprio(0);                                              \
    __builtin_amdgcn_s_barrier();  /* all buf-d reads complete block-wide */    \
    STAGE8(d, pre_koff);                                                        \
    __builtin_amdgcn_s_setprio(1);                                              \
    acc[2][0] = MFMA16(a20, b00, acc[2][0]); acc[2][0] = MFMA16(a21, b01, acc[2][0]); \
    acc[2][1] = MFMA16(a20, b10, acc[2][1]); acc[2][1] = MFMA16(a21, b11, acc[2][1]); \
    acc[2][2] = MFMA16(a20, b20, acc[2][2]); acc[2][2] = MFMA16(a21, b21, acc[2][2]); \
    acc[2][3] = MFMA16(a20, b30, acc[2][3]); acc[2][3] = MFMA16(a21, b31, acc[2][3]); \
    acc[3][0] = MFMA16(a30, b00, acc[3][0]); acc[3][0] = MFMA16(a31, b01, acc[3][0]); \
    acc[3][1] = MFMA16(a30, b10, acc[3][1]); acc[3][1] = MFMA16(a31, b11, acc[3][1]); \
    acc[3][2] = MFMA16(a30, b20, acc[3][2]); acc[3][2] = MFMA16(a31, b21, acc[3][2]); \
    acc[3][3] = MFMA16(a30, b30, acc[3][3]); acc[3][3] = MFMA16(a31, b31, acc[3][3]); \
    __builtin_amdgcn_s_setprio(0);                                              \
    asm volatile("s_waitcnt vmcnt(8)" ::: "memory");                            \
    __builtin_amdgcn_s_barrier();                                               \
  } while (0)

__device__ __forceinline__ void gemm_core_128x128(
    const u16* __restrict__ A, const u16* __restrict__ Bt,
    int m0, int n0, u16* lds, f32x4 (&acc)[4][4]) {
  const int tid = threadIdx.x;               // 0..255
  const int wid = tid >> 6, lane = tid & 63;
  const int llo = lane & 15, lhi16 = (lane >> 4) * 16;
  const int wm = (wid >> 1) * 64;
  const int wn = (wid & 1) * 64;
  const int K = HIDN;

  // pre-swizzled per-lane global source pointers (linear LDS dest, m173).
  // A tile [128][64]u16 = 16KB; chunk q covers bytes q*4096 + t*16.
  const u16* gA[4];
  const u16* gB[4];
#pragma unroll
  for (int q = 0; q < 4; ++q) {
    int off = q * 4096 + tid * 16;
    int s = swz(off);
    gA[q] = A + (size_t)(m0 + (s >> 7)) * K + ((s & 127) >> 1);
    gB[q] = Bt + (size_t)(n0 + (s >> 7)) * K + ((s & 127) >> 1);
  }
  // LDS layout (u16): dbuf d at d*16384: A[8192], B[8192]  (64KB total)
  u16* lA[2] = { lds, lds + 16384 };
  u16* lB[2] = { lds + 8192, lds + 16384 + 8192 };
  const int wq = wid * 512;  // wave-uniform chunk (1KB per wave per load)

#pragma unroll
  for (int i = 0; i < 4; ++i)
#pragma unroll
    for (int j = 0; j < 4; ++j) acc[i][j] = (f32x4){0.f, 0.f, 0.f, 0.f};

  // prologue: stage k-tiles 0,1; wait tile 0 only (counted)
  STAGE8(0, 0);
  STAGE8(1, 64);
  asm volatile("s_waitcnt vmcnt(8)" ::: "memory");
  __builtin_amdgcn_s_barrier();

#pragma unroll 1
  for (int kt = 0; kt < 32; kt += 2) {
    int p0 = (kt + 2 < 32) ? (kt + 2) * 64 : 0;  // clamped dummy tail prefetch
    int p1 = (kt + 3 < 32) ? (kt + 3) * 64 : 0;
    KTILE(0, p0);
    KTILE(1, p1);
  }
}

// ---------------- QKV GEMM: [4096,2048] x Wt[6144,2048] + bias ---------------
// Grid 1536 = 32 by x 48 bx. XCD map: round-8 orientation -- each XCD owns 6
// contiguous bx panels (6x512KB = 3MB, L2-fits) and sweeps all 32 by.
__global__ __launch_bounds__(256, 4) void gemm_qkv8_kernel(
    const u16* __restrict__ A, const u16* __restrict__ Bt,
    const float* __restrict__ bias,
    u16* __restrict__ Qb, u16* __restrict__ Kb, u16* __restrict__ Vt) {
  __shared__ __align__(16) u16 lds[32768];  // 64KB -> 2 blocks/CU
  int bid = blockIdx.x;
  int sb = (bid & 7) * 192 + (bid >> 3);    // per-XCD contiguous range
  int bx = sb >> 5, by = sb & 31;
  int m0 = by * 128, n0 = bx * 128;

  f32x4 acc[4][4];
  gemm_core_128x128(A, Bt, m0, n0, lds, acc);

  const int tid = threadIdx.x;
  const int wid = tid >> 6, lane = tid & 63;
  const int llo = lane & 15, lhi = lane >> 4;
  const int wm = (wid >> 1) * 64, wn = (wid & 1) * 64;

#pragma unroll
  for (int j = 0; j < 4; ++j) {
    int col = n0 + wn + j * 16 + llo;       // 0..6143
    int h = col / 384;
    int rr = col - h * 384;
    int part = rr >> 7;                     // 0=q 1=k 2=v
    int d = rr & 127;
    float bv = bias[col];
#pragma unroll
    for (int i = 0; i < 4; ++i) {
#pragma unroll
      for (int r = 0; r < 4; ++r) {
        int row = m0 + wm + i * 16 + lhi * 4 + r;  // 0..4095
        int s2 = row >> 1, b = row & 1;
        int bh = b * NHEAD + h;
        u16 o = f2bf(acc[i][j][r] + bv);
        if (part == 0)      Qb[((size_t)bh * S_LEN + s2) * DHEAD + d] = o;
        else if (part == 1) Kb[((size_t)bh * S_LEN + s2) * DHEAD + d] = o;
        else                Vt[((size_t)bh * DHEAD + d) * S_LEN + s2] = o;
      }
    }
  }
}

// ------------- dense GEMM: ctx[4096,2048] x Wt[2048,2048] -> fp32 out --------
__global__ __launch_bounds__(256, 4) void gemm_dense8_kernel(
    const u16* __restrict__ A, const u16* __restrict__ Bt,
    float* __restrict__ out) {
  __shared__ __align__(16) u16 lds[32768];  // 64KB
  int bid = blockIdx.x;                      // 512 = 32 by x 16 bx
  int sb = (bid & 7) * 64 + (bid >> 3);      // per-XCD: 2 bx panels x 32 by
  int bx = sb >> 5, by = sb & 31;
  int m0 = by * 128, n0 = bx * 128;

  f32x4 acc[4][4];
  gemm_core_128x128(A, Bt, m0, n0, lds, acc);

  const int tid = threadIdx.x;
  const int wid = tid >> 6, lane = tid & 63;
  const int llo = lane & 15, lhi = lane >> 4;
  const int wm = (wid >> 1) * 64, wn = (wid & 1) * 64;

#pragma unroll
  for (int i = 0; i < 4; ++i)
#pragma unroll
    for (int j = 0; j < 4; ++j) {
      int col = n0 + wn + j * 16 + llo;
#pragma unroll
      for (int r = 0; r < 4; ++r) {
        int row = m0 + wm + i * 16 + lhi * 4 + r;
        out[(size_t)row * HIDN + col] = acc[i][j][r];
      }
    }
}

// ---------------- flash attention (causal), one block per (q-tile, bh) -------
// (unchanged from round 8 -- passed; global_load_lds double-buffer, no spill)
__global__ __launch_bounds__(512, 2) void attn_kernel(
    const u16* __restrict__ Qb, const u16* __restrict__ Kb,
    const u16* __restrict__ Vt, u16* __restrict__ ctx) {
  const int bh = blockIdx.y;   // 0..31
  const int b = bh >> 4, h = bh & 15;
  const int qi = (b == 0) ? blockIdx.x : (15 - blockIdx.x);
  const int tid = threadIdx.x;
  const int wave = tid >> 6, lane = tid & 63;
  const int lhi = lane >> 4, llo = lane & 15;
  __shared__ __align__(16) u16 lds[65536];  // 128KB: 2 x [K 16384 | V 16384] u16

  const int srow = tid >> 4;                                  // 0..31
  const int scs = ((tid & 15) * 16) ^ ((srow & 7) << 4);      // swizzled byte col
  const int sc2 = scs >> 1;                                   // u16 col
  const u16* kbase = Kb + (size_t)bh * S_LEN * DHEAD;
  const u16* vbase = Vt + (size_t)bh * DHEAD * S_LEN;

#define ASTAGE(T, DST) do {                                                        \
    const u16* ks_ = kbase + (size_t)(T) * 128 * DHEAD;                            \
    const u16* vs_ = vbase + (T) * 128;                                            \
    _Pragma("unroll")                                                              \
    for (int p = 0; p < 4; ++p) {                                                  \
      async_cp16(ks_ + (size_t)(p * 32 + srow) * DHEAD + sc2,                      \
                 (DST) + p * 4096 + wave * 512);                                   \
      async_cp16(vs_ + (size_t)(p * 32 + srow) * S_LEN + sc2,                      \
                 (DST) + 16384 + p * 4096 + wave * 512);                           \
    }                                                                              \
  } while (0)

  bf16x8 aq[4];
  {
    const u16* qsrc = Qb + ((size_t)bh * S_LEN + qi * 128) * DHEAD;
#pragma unroll
    for (int kk = 0; kk < 4; kk++)
      aq[kk] = *(const bf16x8*)&qsrc[(size_t)(wave * 16 + llo) * DHEAD + kk * 32 + lhi * 8];
  }

  f32x4 oacc[8] = {};
  float mrow[4], lrow[4];
#pragma unroll
  for (int r = 0; r < 4; r++) { mrow[r] = -1e30f; lrow[r] = 0.f; }
  const float sc = 0.08838834764831845f;  // 1/sqrt(128)

  int bcol[4];
#pragma unroll
  for (int kk = 0; kk < 4; kk++)
    bcol[kk] = ((kk * 64 + lhi * 16) ^ ((llo & 7) << 4)) >> 1;

  ASTAGE(0, lds);
  asm volatile("s_waitcnt vmcnt(0)" ::: "memory");
  __builtin_amdgcn_s_barrier();
  asm volatile("" ::: "memory");

  for (int kt = 0; kt <= qi; kt++) {
    const int cur = kt & 1;
    u16* Kc = lds + cur * 32768;         // K tile / later P (aliased)
    u16* Vc = Kc + 16384;                // V^T tile [d][t]

    if (kt < qi) ASTAGE(kt + 1, lds + (cur ^ 1) * 32768);

    f32x4 sacc[8] = {};
    __builtin_amdgcn_s_setprio(1);
#pragma unroll
    for (int kk = 0; kk < 4; kk++) {
#pragma unroll
      for (int j = 0; j < 8; j++) {
        bf16x8 bk = *(const bf16x8*)&Kc[(j * 16 + llo) * 128 + bcol[kk]];
        sacc[j] = MFMA16(aq[kk], bk, sacc[j]);
      }
    }
    __builtin_amdgcn_s_setprio(0);
    asm volatile("" ::: "memory");
    __builtin_amdgcn_s_barrier();
    asm volatile("" ::: "memory");

    if (kt == qi) {
#pragma unroll
      for (int j = 0; j < 8; j++) {
        int coll = j * 16 + llo;
#pragma unroll
        for (int r = 0; r < 4; r++) {
          int rowl = wave * 16 + lhi * 4 + r;
          if (coll > rowl) sacc[j][r] = -1e30f;
        }
      }
    }

#pragma unroll
    for (int r = 0; r < 4; r++) {
      float mx = sacc[0][r];
#pragma unroll
      for (int j = 1; j < 8; j++) mx = fmaxf(mx, sacc[j][r]);
#pragma unroll
      for (int off = 1; off < 16; off <<= 1)
        mx = fmaxf(mx, __shfl_xor(mx, off, 64));
      float mnew = fmaxf(mrow[r], mx);
      float al = __expf((mrow[r] - mnew) * sc);
      mrow[r] = mnew;
      float rs = 0.f;
#pragma unroll
      for (int j = 0; j < 8; j++) {
        float e = __expf((sacc[j][r] - mnew) * sc);
        sacc[j][r] = e;
        rs += e;
        oacc[j][r] *= al;
      }
#pragma unroll
      for (int off = 1; off < 16; off <<= 1)
        rs += __shfl_xor(rs, off, 64);
      lrow[r] = lrow[r] * al + rs;
    }

#pragma unroll
    for (int j = 0; j < 8; j++)
#pragma unroll
      for (int r = 0; r < 4; r++) {
        int pr = wave * 16 + lhi * 4 + r;
        int cb = (j * 16 + llo) * 2;
        Kc[pr * 128 + ((cb ^ ((pr & 7) << 4)) >> 1)] = f2bf(sacc[j][r]);
      }

    __builtin_amdgcn_s_setprio(1);
#pragma unroll
    for (int kk = 0; kk < 4; kk++) {
      bf16x8 ap = *(const bf16x8*)&Kc[(wave * 16 + llo) * 128 + bcol[kk]];
#pragma unroll
      for (int j = 0; j < 8; j++) {
        bf16x8 bv = *(const bf16x8*)&Vc[(j * 16 + llo) * 128 + bcol[kk]];
        oacc[j] = MFMA16(ap, bv, oacc[j]);
      }
    }
    __builtin_amdgcn_s_setprio(0);

    asm volatile("s_waitcnt vmcnt(0)" ::: "memory");
    asm volatile("" ::: "memory");
    __builtin_amdgcn_s_barrier();
    asm volatile("" ::: "memory");
  }
#undef ASTAGE

  float inv[4];
#pragma unroll
  for (int r = 0; r < 4; r++) inv[r] = 1.f / lrow[r];
#pragma unroll
  for (int j = 0; j < 8; j++) {
    int d = j * 16 + llo;
#pragma unroll
    for (int r = 0; r < 4; r++) {
      int s = qi * 128 + wave * 16 + lhi * 4 + r;
      ctx[((size_t)(s * BATCH + b)) * HIDN + h * DHEAD + d] = f2bf(oacc[j][r] * inv[r]);
    }
  }
}

// ---------------- bias tail: fp32 copy into output slot 1 --------------------
__global__ __launch_bounds__(256) void bias_copy_kernel(
    const float* __restrict__ bsrc, float* __restrict__ dst) {
  int i = blockIdx.x * 256 + threadIdx.x;
  if (i < HIDN) dst[i] = bsrc[i];
}

extern "C" void kernel_launch(void* const* d_in, const int* in_sizes, int n_in,
                              void* d_out, int out_size, void* d_ws, size_t ws_size,
                              hipStream_t stream) {
  int i_hid = 0, i_w1 = 2, i_b1 = 3, i_w2 = 4, i_b2 = 5;
  for (int i = 0; i < n_in; i++) {
    int s = in_sizes[i];
    if (s == MROWS * HIDN)      i_hid = i;
    else if (s == HIDN * NQKV)  i_w1 = i;
    else if (s == NQKV)         i_b1 = i;
    else if (s == HIDN)         i_b2 = i;
  }
  for (int i = n_in - 1; i >= 0; i--)
    if (in_sizes[i] == HIDN * HIDN) { i_w2 = i; break; }

  const float* hidden  = (const float*)d_in[i_hid];
  const float* W_qkv   = (const float*)d_in[i_w1];
  const float* b_qkv   = (const float*)d_in[i_b1];
  const float* W_dense = (const float*)d_in[i_w2];
  const float* b_dense = (const float*)d_in[i_b2];
  float* out = (float*)d_out;

  char* ws = (char*)d_ws;
  u16* Wq_t = (u16*)(ws);
  u16* ctx  = (u16*)(ws);
  u16* Wd_t = (u16*)(ws + 16777216);
  u16* Qb   = (u16*)(ws + 25165824);
  u16* Kb   = (u16*)(ws + 41943040);
  u16* Vt   = (u16*)(ws + 58720256);
  u16* hidden_c = (u16*)d_out;

  convert_hidden_kernel<<<dim3(MROWS * HIDN / 8 / 256), 256, 0, stream>>>(hidden, hidden_c);
  transpose_kernel<<<dim3(NQKV / 64, HIDN / 64), 256, 0, stream>>>(W_qkv, Wq_t, HIDN, NQKV);
  gemm_qkv8_kernel<<<dim3(1536), dim3(256), 0, stream>>>(hidden_c, Wq_t, b_qkv, Qb, Kb, Vt);
  attn_kernel<<<dim3(S_LEN / 128, BATCH * NHEAD), dim3(512), 0, stream>>>(Qb, Kb, Vt, ctx);
  transpose_kernel<<<dim3(HIDN / 64, HIDN / 64), 256, 0, stream>>>(W_dense, Wd_t, HIDN, HIDN);
  gemm_dense8_kernel<<<dim3(512), dim3(256), 0, stream>>>(ctx, Wd_t, out);
  bias_copy_kernel<<<dim3(8), 256, 0, stream>>>(b_dense, out + (size_t)MROWS * HIDN);
}